// Round 1
// baseline (1435.228 us; speedup 1.0000x reference)
//
#include <hip/hip_runtime.h>
#include <hip/hip_bf16.h>
#include <math.h>

#define N_NODES 50000
#define N_EDGES 640000
#define NGRAPH  256
#define SCHUNK  1024
#define NCHUNK  49   // ceil(50000/1024)

// ------------------------------------------------------------------
// GEMM: C[M,128] = A[M,128] @ W[128,128] (+bias). Optionally fuses the
// attention projections a_s[n,h] = <wx[n,h,:], asrc[h,:]>, a_d likewise.
// Block: 256 threads, 64 rows (2 per thread), 16 cols per thread.
// W staged in LDS (64KB). Col mapping col = m*32 + cg*4 + j  -> head = m.
// ------------------------------------------------------------------
__global__ __launch_bounds__(256) void k_gemm(
    const float* __restrict__ A, const float* __restrict__ W,
    const float* __restrict__ bias, float* __restrict__ C, int M,
    const float* __restrict__ asrc, const float* __restrict__ adst,
    float* __restrict__ a_s, float* __restrict__ a_d)
{
    __shared__ float Ws[128 * 128];
    int tid = threadIdx.x;
    {   // stage W into LDS
        const float4* Wg = (const float4*)W;
        float4* Wl = (float4*)Ws;
        #pragma unroll
        for (int i = 0; i < 16; ++i) Wl[i * 256 + tid] = Wg[i * 256 + tid];
    }
    __syncthreads();

    int cg = tid & 7;
    int r0 = blockIdx.x * 64 + (tid >> 3);
    int r1 = r0 + 32;
    bool v0 = r0 < M, v1 = r1 < M;
    float acc0[16], acc1[16];
    #pragma unroll
    for (int i = 0; i < 16; ++i) { acc0[i] = 0.f; acc1[i] = 0.f; }

    const float* A0 = A + (size_t)r0 * 128;
    const float* A1 = A + (size_t)r1 * 128;

    for (int kk = 0; kk < 128; kk += 16) {
        float4 a0[4], a1[4];
        #pragma unroll
        for (int j = 0; j < 4; ++j) {
            a0[j] = v0 ? *(const float4*)(A0 + kk + j * 4) : make_float4(0, 0, 0, 0);
            a1[j] = v1 ? *(const float4*)(A1 + kk + j * 4) : make_float4(0, 0, 0, 0);
        }
        #pragma unroll
        for (int k2 = 0; k2 < 16; ++k2) {
            float av0 = ((const float*)a0)[k2];
            float av1 = ((const float*)a1)[k2];
            #pragma unroll
            for (int m = 0; m < 4; ++m) {
                float4 w = *(const float4*)&Ws[(kk + k2) * 128 + (cg << 2) + (m << 5)];
                acc0[m * 4 + 0] += av0 * w.x; acc0[m * 4 + 1] += av0 * w.y;
                acc0[m * 4 + 2] += av0 * w.z; acc0[m * 4 + 3] += av0 * w.w;
                acc1[m * 4 + 0] += av1 * w.x; acc1[m * 4 + 1] += av1 * w.y;
                acc1[m * 4 + 2] += av1 * w.z; acc1[m * 4 + 3] += av1 * w.w;
            }
        }
    }

    // store C (+ bias)
    #pragma unroll
    for (int m = 0; m < 4; ++m) {
        float4 o0 = make_float4(acc0[m*4], acc0[m*4+1], acc0[m*4+2], acc0[m*4+3]);
        float4 o1 = make_float4(acc1[m*4], acc1[m*4+1], acc1[m*4+2], acc1[m*4+3]);
        if (bias) {
            float4 bb = *(const float4*)&bias[(m << 5) + (cg << 2)];
            o0.x += bb.x; o0.y += bb.y; o0.z += bb.z; o0.w += bb.w;
            o1.x += bb.x; o1.y += bb.y; o1.z += bb.z; o1.w += bb.w;
        }
        if (v0) *(float4*)&C[(size_t)r0 * 128 + (m << 5) + (cg << 2)] = o0;
        if (v1) *(float4*)&C[(size_t)r1 * 128 + (m << 5) + (cg << 2)] = o1;
    }

    // fused attention projections
    if (a_s) {
        float s0[4] = {0,0,0,0}, d0[4] = {0,0,0,0};
        float s1[4] = {0,0,0,0}, d1[4] = {0,0,0,0};
        #pragma unroll
        for (int m = 0; m < 4; ++m) {
            #pragma unroll
            for (int j = 0; j < 4; ++j) {
                float wsv = asrc[(m << 5) + (cg << 2) + j];
                float wdv = adst[(m << 5) + (cg << 2) + j];
                s0[m] += acc0[m * 4 + j] * wsv; d0[m] += acc0[m * 4 + j] * wdv;
                s1[m] += acc1[m * 4 + j] * wsv; d1[m] += acc1[m * 4 + j] * wdv;
            }
        }
        #pragma unroll
        for (int m = 0; m < 4; ++m) {
            #pragma unroll
            for (int k = 1; k < 8; k <<= 1) {
                s0[m] += __shfl_xor(s0[m], k);
                d0[m] += __shfl_xor(d0[m], k);
                s1[m] += __shfl_xor(s1[m], k);
                d1[m] += __shfl_xor(d1[m], k);
            }
        }
        if (cg == 0) {
            #pragma unroll
            for (int m = 0; m < 4; ++m) {
                if (v0) { a_s[r0 * 4 + m] = s0[m]; a_d[r0 * 4 + m] = d0[m]; }
                if (v1) { a_s[r1 * 4 + m] = s1[m]; a_d[r1 * 4 + m] = d1[m]; }
            }
        }
    }
}

// ------------------------------------------------------------------
// CSR build
// ------------------------------------------------------------------
__global__ void k_zero_i(int* p, int n) {
    int i = blockIdx.x * blockDim.x + threadIdx.x;
    if (i < n) p[i] = 0;
}

__global__ void k_deg(const int* __restrict__ dst, int* deg) {
    int e = blockIdx.x * blockDim.x + threadIdx.x;
    if (e < N_EDGES) atomicAdd(&deg[dst[e]], 1);
}

__global__ __launch_bounds__(256) void k_chunksum(const int* __restrict__ deg, int* cs) {
    __shared__ int r[256];
    int b = blockIdx.x;
    int acc = 0;
    for (int i = threadIdx.x; i < SCHUNK; i += 256) {
        int idx = b * SCHUNK + i;
        if (idx < N_NODES) acc += deg[idx];
    }
    r[threadIdx.x] = acc; __syncthreads();
    for (int s = 128; s > 0; s >>= 1) {
        if (threadIdx.x < s) r[threadIdx.x] += r[threadIdx.x + s];
        __syncthreads();
    }
    if (threadIdx.x == 0) cs[b] = r[0];
}

__global__ void k_scanbase(const int* cs, int* base, int* offs) {
    if (threadIdx.x == 0) {
        int run = 0;
        for (int b = 0; b < NCHUNK; ++b) { base[b] = run; run += cs[b]; }
        offs[N_NODES] = run;
    }
}

__global__ __launch_bounds__(1024) void k_scanlocal(
    const int* __restrict__ deg, const int* __restrict__ base,
    int* offs, int* cursor)
{
    __shared__ int s[1024];
    int b = blockIdx.x, t = threadIdx.x;
    int idx = b * SCHUNK + t;
    int d = (idx < N_NODES) ? deg[idx] : 0;
    s[t] = d; __syncthreads();
    for (int off = 1; off < 1024; off <<= 1) {
        int v = (t >= off) ? s[t - off] : 0;
        __syncthreads();
        s[t] += v; __syncthreads();
    }
    if (idx < N_NODES) {
        int ex = s[t] - d + base[b];
        offs[idx] = ex; cursor[idx] = ex;
    }
}

__global__ void k_fill(const int* __restrict__ dst, int* cursor, int* csr) {
    int e = blockIdx.x * blockDim.x + threadIdx.x;
    if (e < N_EDGES) { int p = atomicAdd(&cursor[dst[e]], 1); csr[p] = e; }
}

// ------------------------------------------------------------------
// Aggregation: one wave per destination node. Two passes over incident
// edges: (1) per-head max, (2) exp-weighted gather of wx[src] + denom.
// Epilogue: divide, elu, optional residual. No atomics.
// ------------------------------------------------------------------
__global__ __launch_bounds__(256) void k_agg(
    const float* __restrict__ wx, const float* __restrict__ a_s,
    const float* __restrict__ a_d, const float* __restrict__ ea,
    const int* __restrict__ src, const int* __restrict__ csr,
    const int* __restrict__ offs, const float* __restrict__ resid,
    float* __restrict__ out)
{
    int lane = threadIdx.x & 63;
    int n = blockIdx.x * 4 + (threadIdx.x >> 6);
    int ht = lane >> 4;           // head of this lane's columns
    int col = lane * 2;
    int off0 = offs[n], off1 = offs[n + 1];
    float adn = a_d[n * 4 + ht];

    float mx = -3.0e38f;
    for (int i = off0; i < off1; ++i) {
        int e = csr[i];
        int s = src[e];
        float va = a_s[s * 4 + ht] + adn;
        float v = (va > 0.f ? va : 0.2f * va) * ea[e];
        mx = fmaxf(mx, v);
    }
    float den = 0.f, acc0 = 0.f, acc1 = 0.f;
    for (int i = off0; i < off1; ++i) {
        int e = csr[i];
        int s = src[e];
        float va = a_s[s * 4 + ht] + adn;
        float v = (va > 0.f ? va : 0.2f * va) * ea[e];
        float w = __expf(v - mx);
        den += w;
        float2 wv = *(const float2*)&wx[(size_t)s * 128 + col];
        acc0 += w * wv.x; acc1 += w * wv.y;
    }
    float inv = 1.f / (den + 1e-16f);
    float r0 = acc0 * inv, r1 = acc1 * inv;
    r0 = r0 > 0.f ? r0 : expm1f(r0);
    r1 = r1 > 0.f ? r1 : expm1f(r1);
    if (resid) {
        float2 rv = *(const float2*)&resid[(size_t)n * 128 + col];
        r0 += rv.x; r1 += rv.y;
    }
    float2 o; o.x = r0; o.y = r1;
    *(float2*)&out[(size_t)n * 128 + col] = o;
}

// ------------------------------------------------------------------
// Global add pool: batch is sorted, binary search the segment.
// ------------------------------------------------------------------
__global__ __launch_bounds__(128) void k_pool(
    const float* __restrict__ h, const int* __restrict__ batch,
    float* __restrict__ pooled)
{
    __shared__ int ss, se;
    int g = blockIdx.x;
    if (threadIdx.x == 0) {
        int lo = 0, hi = N_NODES;
        while (lo < hi) { int mid = (lo + hi) >> 1; if (batch[mid] < g) lo = mid + 1; else hi = mid; }
        ss = lo;
        lo = 0; hi = N_NODES;
        while (lo < hi) { int mid = (lo + hi) >> 1; if (batch[mid] < g + 1) lo = mid + 1; else hi = mid; }
        se = lo;
    }
    __syncthreads();
    float acc = 0.f;
    for (int n = ss; n < se; ++n) acc += h[(size_t)n * 128 + threadIdx.x];
    pooled[g * 128 + threadIdx.x] = acc;
}

// ------------------------------------------------------------------
// Linear + BatchNorm (+relu). One block per output column, thread=graph.
// ------------------------------------------------------------------
template <int K, int OC>
__global__ __launch_bounds__(256) void k_mlp(
    const float* __restrict__ in, const float* __restrict__ w,
    const float* __restrict__ b, const float* __restrict__ gam,
    const float* __restrict__ bet, float* __restrict__ out, int do_relu)
{
    __shared__ float2 red[256];
    int c = blockIdx.x, g = threadIdx.x;
    float val = b[c];
    #pragma unroll 8
    for (int k = 0; k < K; ++k) val += in[g * K + k] * w[k * OC + c];
    red[g] = make_float2(val, val * val);
    __syncthreads();
    for (int s = 128; s > 0; s >>= 1) {
        if (g < s) { red[g].x += red[g + s].x; red[g].y += red[g + s].y; }
        __syncthreads();
    }
    float mean = red[0].x * (1.f / 256.f);
    float var = red[0].y * (1.f / 256.f) - mean * mean;
    float y = (val - mean) * rsqrtf(var + 1e-5f) * gam[c] + bet[c];
    if (do_relu) y = fmaxf(y, 0.f);
    out[g * OC + c] = y;
}

// ------------------------------------------------------------------
extern "C" void kernel_launch(void* const* d_in, const int* in_sizes, int n_in,
                              void* d_out, int out_size, void* d_ws, size_t ws_size,
                              hipStream_t stream)
{
    const float* x         = (const float*)d_in[0];
    const float* edge_attr = (const float*)d_in[1];
    const float* lin_w     = (const float*)d_in[2];
    const float* lin_b     = (const float*)d_in[3];
    const float* conv_W    = (const float*)d_in[4];   // [3,2,128,128]
    const float* conv_asrc = (const float*)d_in[5];   // [3,2,4,32]
    const float* conv_adst = (const float*)d_in[6];
    const float* fc_w1 = (const float*)d_in[7];
    const float* fc_b1 = (const float*)d_in[8];
    const float* bn_g1 = (const float*)d_in[9];
    const float* bn_b1 = (const float*)d_in[10];
    const float* fc_w2 = (const float*)d_in[11];
    const float* fc_b2 = (const float*)d_in[12];
    const float* bn_g2 = (const float*)d_in[13];
    const float* bn_b2 = (const float*)d_in[14];
    const float* fc_w3 = (const float*)d_in[15];
    const float* fc_b3 = (const float*)d_in[16];
    const float* bn_g3 = (const float*)d_in[17];
    const float* bn_b3 = (const float*)d_in[18];
    const int* edge_index = (const int*)d_in[19];     // [2,E]
    const int* batch      = (const int*)d_in[20];
    const int* srcp = edge_index;
    const int* dstp = edge_index + N_EDGES;
    float* out = (float*)d_out;

    char* ws = (char*)d_ws;
    float* h_cur = (float*)ws;  ws += (size_t)N_NODES * 128 * 4;
    float* h_tmp = (float*)ws;  ws += (size_t)N_NODES * 128 * 4;
    float* wx    = (float*)ws;  ws += (size_t)N_NODES * 128 * 4;
    float* a_s   = (float*)ws;  ws += (size_t)N_NODES * 4 * 4;
    float* a_d   = (float*)ws;  ws += (size_t)N_NODES * 4 * 4;
    float* pooled= (float*)ws;  ws += (size_t)NGRAPH * 128 * 4;
    float* z1    = (float*)ws;  ws += (size_t)NGRAPH * 64 * 4;
    float* z2    = (float*)ws;  ws += (size_t)NGRAPH * 32 * 4;
    int* deg     = (int*)ws;    ws += (size_t)N_NODES * 4;
    int* offs    = (int*)ws;    ws += (size_t)(N_NODES + 4) * 4;
    int* cursor  = (int*)ws;    ws += (size_t)N_NODES * 4;
    int* csr     = (int*)ws;    ws += (size_t)N_EDGES * 4;
    int* cs      = (int*)ws;    ws += 64 * 4;
    int* cbase   = (int*)ws;    ws += 64 * 4;

    // --- CSR build ---
    k_zero_i<<<(N_NODES + 255) / 256, 256, 0, stream>>>(deg, N_NODES);
    k_deg<<<(N_EDGES + 255) / 256, 256, 0, stream>>>(dstp, deg);
    k_chunksum<<<NCHUNK, 256, 0, stream>>>(deg, cs);
    k_scanbase<<<1, 64, 0, stream>>>(cs, cbase, offs);
    k_scanlocal<<<NCHUNK, 1024, 0, stream>>>(deg, cbase, offs, cursor);
    k_fill<<<(N_EDGES + 255) / 256, 256, 0, stream>>>(dstp, cursor, csr);

    const int GGRID = (N_NODES + 63) / 64;   // 782

    // --- input linear ---
    k_gemm<<<GGRID, 256, 0, stream>>>(x, lin_w, lin_b, h_cur, N_NODES,
                                      nullptr, nullptr, nullptr, nullptr);

    // --- 3 residual scatter convs, 2 inner layers each ---
    for (int i = 0; i < 3; ++i) {
        const float* W0 = conv_W + (size_t)(i * 2 + 0) * 128 * 128;
        const float* W1 = conv_W + (size_t)(i * 2 + 1) * 128 * 128;
        const float* as0 = conv_asrc + (size_t)(i * 2 + 0) * 128;
        const float* as1 = conv_asrc + (size_t)(i * 2 + 1) * 128;
        const float* ad0 = conv_adst + (size_t)(i * 2 + 0) * 128;
        const float* ad1 = conv_adst + (size_t)(i * 2 + 1) * 128;

        k_gemm<<<GGRID, 256, 0, stream>>>(h_cur, W0, nullptr, wx, N_NODES,
                                          as0, ad0, a_s, a_d);
        k_agg<<<N_NODES / 4, 256, 0, stream>>>(wx, a_s, a_d, edge_attr, srcp,
                                               csr, offs, nullptr, h_tmp);
        k_gemm<<<GGRID, 256, 0, stream>>>(h_tmp, W1, nullptr, wx, N_NODES,
                                          as1, ad1, a_s, a_d);
        k_agg<<<N_NODES / 4, 256, 0, stream>>>(wx, a_s, a_d, edge_attr, srcp,
                                               csr, offs, h_cur, h_cur);
    }

    // --- pool + MLP head ---
    k_pool<<<NGRAPH, 128, 0, stream>>>(h_cur, batch, pooled);
    k_mlp<128, 64><<<64, 256, 0, stream>>>(pooled, fc_w1, fc_b1, bn_g1, bn_b1, z1, 1);
    k_mlp<64, 32><<<32, 256, 0, stream>>>(z1, fc_w2, fc_b2, bn_g2, bn_b2, z2, 1);
    k_mlp<32, 10><<<10, 256, 0, stream>>>(z2, fc_w3, fc_b3, bn_g3, bn_b3, out, 0);
}

// Round 2
// 864.225 us; speedup vs baseline: 1.6607x; 1.6607x over previous
//
#include <hip/hip_runtime.h>
#include <hip/hip_fp16.h>
#include <math.h>

#define N_NODES 50000
#define N_EDGES 640000
#define NGRAPH  256
#define SCHUNK  1024
#define NCHUNK  49   // ceil(50000/1024)

// ------------------------------------------------------------------
// GEMM: C[M,128] = A[M,128] @ W[128,128] (+bias). Writes fp32 C and/or
// fp16 C16. Optionally fuses attention projections a_s/a_d.
// Block: 256 threads, 64 rows (2 per thread), 16 cols per thread.
// ------------------------------------------------------------------
__global__ __launch_bounds__(256) void k_gemm(
    const float* __restrict__ A, const float* __restrict__ W,
    const float* __restrict__ bias, float* __restrict__ C,
    __half* __restrict__ C16, int M,
    const float* __restrict__ asrc, const float* __restrict__ adst,
    float* __restrict__ a_s, float* __restrict__ a_d)
{
    __shared__ float Ws[128 * 128];
    int tid = threadIdx.x;
    {
        const float4* Wg = (const float4*)W;
        float4* Wl = (float4*)Ws;
        #pragma unroll
        for (int i = 0; i < 16; ++i) Wl[i * 256 + tid] = Wg[i * 256 + tid];
    }
    __syncthreads();

    int cg = tid & 7;
    int r0 = blockIdx.x * 64 + (tid >> 3);
    int r1 = r0 + 32;
    bool v0 = r0 < M, v1 = r1 < M;
    float acc0[16], acc1[16];
    #pragma unroll
    for (int i = 0; i < 16; ++i) { acc0[i] = 0.f; acc1[i] = 0.f; }

    const float* A0 = A + (size_t)r0 * 128;
    const float* A1 = A + (size_t)r1 * 128;

    for (int kk = 0; kk < 128; kk += 16) {
        float4 a0[4], a1[4];
        #pragma unroll
        for (int j = 0; j < 4; ++j) {
            a0[j] = v0 ? *(const float4*)(A0 + kk + j * 4) : make_float4(0, 0, 0, 0);
            a1[j] = v1 ? *(const float4*)(A1 + kk + j * 4) : make_float4(0, 0, 0, 0);
        }
        #pragma unroll
        for (int k2 = 0; k2 < 16; ++k2) {
            float av0 = ((const float*)a0)[k2];
            float av1 = ((const float*)a1)[k2];
            #pragma unroll
            for (int m = 0; m < 4; ++m) {
                float4 w = *(const float4*)&Ws[(kk + k2) * 128 + (cg << 2) + (m << 5)];
                acc0[m * 4 + 0] += av0 * w.x; acc0[m * 4 + 1] += av0 * w.y;
                acc0[m * 4 + 2] += av0 * w.z; acc0[m * 4 + 3] += av0 * w.w;
                acc1[m * 4 + 0] += av1 * w.x; acc1[m * 4 + 1] += av1 * w.y;
                acc1[m * 4 + 2] += av1 * w.z; acc1[m * 4 + 3] += av1 * w.w;
            }
        }
    }

    #pragma unroll
    for (int m = 0; m < 4; ++m) {
        float4 o0 = make_float4(acc0[m*4], acc0[m*4+1], acc0[m*4+2], acc0[m*4+3]);
        float4 o1 = make_float4(acc1[m*4], acc1[m*4+1], acc1[m*4+2], acc1[m*4+3]);
        if (bias) {
            float4 bb = *(const float4*)&bias[(m << 5) + (cg << 2)];
            o0.x += bb.x; o0.y += bb.y; o0.z += bb.z; o0.w += bb.w;
            o1.x += bb.x; o1.y += bb.y; o1.z += bb.z; o1.w += bb.w;
        }
        int coff = (m << 5) + (cg << 2);
        if (C) {
            if (v0) *(float4*)&C[(size_t)r0 * 128 + coff] = o0;
            if (v1) *(float4*)&C[(size_t)r1 * 128 + coff] = o1;
        }
        if (C16) {
            __half2 h0a = __floats2half2_rn(o0.x, o0.y);
            __half2 h0b = __floats2half2_rn(o0.z, o0.w);
            __half2 h1a = __floats2half2_rn(o1.x, o1.y);
            __half2 h1b = __floats2half2_rn(o1.z, o1.w);
            if (v0) { *(__half2*)&C16[(size_t)r0 * 128 + coff] = h0a;
                      *(__half2*)&C16[(size_t)r0 * 128 + coff + 2] = h0b; }
            if (v1) { *(__half2*)&C16[(size_t)r1 * 128 + coff] = h1a;
                      *(__half2*)&C16[(size_t)r1 * 128 + coff + 2] = h1b; }
        }
    }

    if (a_s) {
        float s0[4] = {0,0,0,0}, d0[4] = {0,0,0,0};
        float s1[4] = {0,0,0,0}, d1[4] = {0,0,0,0};
        #pragma unroll
        for (int m = 0; m < 4; ++m) {
            #pragma unroll
            for (int j = 0; j < 4; ++j) {
                float wsv = asrc[(m << 5) + (cg << 2) + j];
                float wdv = adst[(m << 5) + (cg << 2) + j];
                s0[m] += acc0[m * 4 + j] * wsv; d0[m] += acc0[m * 4 + j] * wdv;
                s1[m] += acc1[m * 4 + j] * wsv; d1[m] += acc1[m * 4 + j] * wdv;
            }
        }
        #pragma unroll
        for (int m = 0; m < 4; ++m) {
            #pragma unroll
            for (int k = 1; k < 8; k <<= 1) {
                s0[m] += __shfl_xor(s0[m], k);
                d0[m] += __shfl_xor(d0[m], k);
                s1[m] += __shfl_xor(s1[m], k);
                d1[m] += __shfl_xor(d1[m], k);
            }
        }
        if (cg == 0) {
            #pragma unroll
            for (int m = 0; m < 4; ++m) {
                if (v0) { a_s[r0 * 4 + m] = s0[m]; a_d[r0 * 4 + m] = d0[m]; }
                if (v1) { a_s[r1 * 4 + m] = s1[m]; a_d[r1 * 4 + m] = d1[m]; }
            }
        }
    }
}

// ------------------------------------------------------------------
// CSR build
// ------------------------------------------------------------------
__global__ void k_zero_i(int* p, int n) {
    int i = blockIdx.x * blockDim.x + threadIdx.x;
    if (i < n) p[i] = 0;
}

__global__ void k_deg(const int* __restrict__ dst, int* deg) {
    int e = blockIdx.x * blockDim.x + threadIdx.x;
    if (e < N_EDGES) atomicAdd(&deg[dst[e]], 1);
}

__global__ __launch_bounds__(256) void k_chunksum(const int* __restrict__ deg, int* cs) {
    __shared__ int r[256];
    int b = blockIdx.x;
    int acc = 0;
    for (int i = threadIdx.x; i < SCHUNK; i += 256) {
        int idx = b * SCHUNK + i;
        if (idx < N_NODES) acc += deg[idx];
    }
    r[threadIdx.x] = acc; __syncthreads();
    for (int s = 128; s > 0; s >>= 1) {
        if (threadIdx.x < s) r[threadIdx.x] += r[threadIdx.x + s];
        __syncthreads();
    }
    if (threadIdx.x == 0) cs[b] = r[0];
}

__global__ void k_scanbase(const int* cs, int* base, int* offs) {
    if (threadIdx.x == 0) {
        int run = 0;
        for (int b = 0; b < NCHUNK; ++b) { base[b] = run; run += cs[b]; }
        offs[N_NODES] = run;
    }
}

__global__ __launch_bounds__(1024) void k_scanlocal(
    const int* __restrict__ deg, const int* __restrict__ base,
    int* offs, int* cursor)
{
    __shared__ int s[1024];
    int b = blockIdx.x, t = threadIdx.x;
    int idx = b * SCHUNK + t;
    int d = (idx < N_NODES) ? deg[idx] : 0;
    s[t] = d; __syncthreads();
    for (int off = 1; off < 1024; off <<= 1) {
        int v = (t >= off) ? s[t - off] : 0;
        __syncthreads();
        s[t] += v; __syncthreads();
    }
    if (idx < N_NODES) {
        int ex = s[t] - d + base[b];
        offs[idx] = ex; cursor[idx] = ex;
    }
}

__global__ void k_fill(const int* __restrict__ dst, int* cursor, int* csr) {
    int e = blockIdx.x * blockDim.x + threadIdx.x;
    if (e < N_EDGES) { int p = atomicAdd(&cursor[dst[e]], 1); csr[p] = e; }
}

// ------------------------------------------------------------------
// Alpha: per-node softmax over incident edges. 16 lanes per node.
// Writes CSR-ordered srcs[i], unnormalized weights walpha[i][4], and
// per-node denom[n][4]. Two passes (max, then exp+sum).
// ------------------------------------------------------------------
__global__ __launch_bounds__(256) void k_alpha(
    const float* __restrict__ a_s, const float* __restrict__ a_d,
    const float* __restrict__ ea, const int* __restrict__ src,
    const int* __restrict__ csr, const int* __restrict__ offs,
    int* __restrict__ srcs, float4* __restrict__ walpha,
    float* __restrict__ denom)
{
    int l = threadIdx.x & 15;
    int n = blockIdx.x * 16 + (threadIdx.x >> 4);
    int off0 = offs[n], off1 = offs[n + 1];
    float4 adn = *(const float4*)&a_d[n * 4];

    float m0 = -3e38f, m1 = -3e38f, m2 = -3e38f, m3 = -3e38f;
    for (int i = off0 + l; i < off1; i += 16) {
        int e = csr[i]; int s = src[e];
        float aev = ea[e];
        float4 as4 = *(const float4*)&a_s[s * 4];
        float v0 = as4.x + adn.x; v0 = (v0 > 0.f ? v0 : 0.2f * v0) * aev;
        float v1 = as4.y + adn.y; v1 = (v1 > 0.f ? v1 : 0.2f * v1) * aev;
        float v2 = as4.z + adn.z; v2 = (v2 > 0.f ? v2 : 0.2f * v2) * aev;
        float v3 = as4.w + adn.w; v3 = (v3 > 0.f ? v3 : 0.2f * v3) * aev;
        m0 = fmaxf(m0, v0); m1 = fmaxf(m1, v1);
        m2 = fmaxf(m2, v2); m3 = fmaxf(m3, v3);
    }
    #pragma unroll
    for (int k = 1; k < 16; k <<= 1) {
        m0 = fmaxf(m0, __shfl_xor(m0, k));
        m1 = fmaxf(m1, __shfl_xor(m1, k));
        m2 = fmaxf(m2, __shfl_xor(m2, k));
        m3 = fmaxf(m3, __shfl_xor(m3, k));
    }

    float s0 = 0.f, s1 = 0.f, s2 = 0.f, s3 = 0.f;
    for (int i = off0 + l; i < off1; i += 16) {
        int e = csr[i]; int s = src[e];
        float aev = ea[e];
        float4 as4 = *(const float4*)&a_s[s * 4];
        float v0 = as4.x + adn.x; v0 = (v0 > 0.f ? v0 : 0.2f * v0) * aev;
        float v1 = as4.y + adn.y; v1 = (v1 > 0.f ? v1 : 0.2f * v1) * aev;
        float v2 = as4.z + adn.z; v2 = (v2 > 0.f ? v2 : 0.2f * v2) * aev;
        float v3 = as4.w + adn.w; v3 = (v3 > 0.f ? v3 : 0.2f * v3) * aev;
        float w0 = __expf(v0 - m0), w1 = __expf(v1 - m1);
        float w2 = __expf(v2 - m2), w3 = __expf(v3 - m3);
        walpha[i] = make_float4(w0, w1, w2, w3);
        srcs[i] = s;
        s0 += w0; s1 += w1; s2 += w2; s3 += w3;
    }
    #pragma unroll
    for (int k = 1; k < 16; k <<= 1) {
        s0 += __shfl_xor(s0, k); s1 += __shfl_xor(s1, k);
        s2 += __shfl_xor(s2, k); s3 += __shfl_xor(s3, k);
    }
    if (l == 0) *(float4*)&denom[n * 4] = make_float4(s0, s1, s2, s3);
}

// ------------------------------------------------------------------
// Gather: one wave per destination node. Sequential srcs/walpha reads,
// unroll-4 independent fp16 row gathers. Divide by denom, elu, resid.
// ------------------------------------------------------------------
__global__ __launch_bounds__(256) void k_gather(
    const __half* __restrict__ wx16, const int* __restrict__ srcs,
    const float* __restrict__ walpha, const float* __restrict__ denom,
    const int* __restrict__ offs, const float* __restrict__ resid,
    float* __restrict__ out)
{
    int lane = threadIdx.x & 63;
    int n = blockIdx.x * 4 + (threadIdx.x >> 6);
    int ht = lane >> 4;
    int col = lane * 2;
    int off0 = offs[n], off1 = offs[n + 1];

    float acc0 = 0.f, acc1 = 0.f;
    int i = off0;
    for (; i + 4 <= off1; i += 4) {
        int s0 = srcs[i], s1 = srcs[i + 1], s2 = srcs[i + 2], s3 = srcs[i + 3];
        float w0 = walpha[(size_t)(i    ) * 4 + ht];
        float w1 = walpha[(size_t)(i + 1) * 4 + ht];
        float w2 = walpha[(size_t)(i + 2) * 4 + ht];
        float w3 = walpha[(size_t)(i + 3) * 4 + ht];
        __half2 g0 = *(const __half2*)&wx16[(size_t)s0 * 128 + col];
        __half2 g1 = *(const __half2*)&wx16[(size_t)s1 * 128 + col];
        __half2 g2 = *(const __half2*)&wx16[(size_t)s2 * 128 + col];
        __half2 g3 = *(const __half2*)&wx16[(size_t)s3 * 128 + col];
        float2 f0 = __half22float2(g0), f1 = __half22float2(g1);
        float2 f2 = __half22float2(g2), f3 = __half22float2(g3);
        acc0 += w0 * f0.x + w1 * f1.x + w2 * f2.x + w3 * f3.x;
        acc1 += w0 * f0.y + w1 * f1.y + w2 * f2.y + w3 * f3.y;
    }
    for (; i < off1; ++i) {
        int s = srcs[i];
        float w = walpha[(size_t)i * 4 + ht];
        __half2 g = *(const __half2*)&wx16[(size_t)s * 128 + col];
        float2 f = __half22float2(g);
        acc0 += w * f.x; acc1 += w * f.y;
    }
    float inv = 1.f / (denom[n * 4 + ht] + 1e-16f);
    float r0 = acc0 * inv, r1 = acc1 * inv;
    r0 = r0 > 0.f ? r0 : expm1f(r0);
    r1 = r1 > 0.f ? r1 : expm1f(r1);
    if (resid) {
        float2 rv = *(const float2*)&resid[(size_t)n * 128 + col];
        r0 += rv.x; r1 += rv.y;
    }
    float2 o; o.x = r0; o.y = r1;
    *(float2*)&out[(size_t)n * 128 + col] = o;
}

// ------------------------------------------------------------------
// Global add pool
// ------------------------------------------------------------------
__global__ __launch_bounds__(128) void k_pool(
    const float* __restrict__ h, const int* __restrict__ batch,
    float* __restrict__ pooled)
{
    __shared__ int ss, se;
    int g = blockIdx.x;
    if (threadIdx.x == 0) {
        int lo = 0, hi = N_NODES;
        while (lo < hi) { int mid = (lo + hi) >> 1; if (batch[mid] < g) lo = mid + 1; else hi = mid; }
        ss = lo;
        lo = 0; hi = N_NODES;
        while (lo < hi) { int mid = (lo + hi) >> 1; if (batch[mid] < g + 1) lo = mid + 1; else hi = mid; }
        se = lo;
    }
    __syncthreads();
    float acc = 0.f;
    for (int n = ss; n < se; ++n) acc += h[(size_t)n * 128 + threadIdx.x];
    pooled[g * 128 + threadIdx.x] = acc;
}

// ------------------------------------------------------------------
// Linear + BatchNorm (+relu)
// ------------------------------------------------------------------
template <int K, int OC>
__global__ __launch_bounds__(256) void k_mlp(
    const float* __restrict__ in, const float* __restrict__ w,
    const float* __restrict__ b, const float* __restrict__ gam,
    const float* __restrict__ bet, float* __restrict__ out, int do_relu)
{
    __shared__ float2 red[256];
    int c = blockIdx.x, g = threadIdx.x;
    float val = b[c];
    #pragma unroll 8
    for (int k = 0; k < K; ++k) val += in[g * K + k] * w[k * OC + c];
    red[g] = make_float2(val, val * val);
    __syncthreads();
    for (int s = 128; s > 0; s >>= 1) {
        if (g < s) { red[g].x += red[g + s].x; red[g].y += red[g + s].y; }
        __syncthreads();
    }
    float mean = red[0].x * (1.f / 256.f);
    float var = red[0].y * (1.f / 256.f) - mean * mean;
    float y = (val - mean) * rsqrtf(var + 1e-5f) * gam[c] + bet[c];
    if (do_relu) y = fmaxf(y, 0.f);
    out[g * OC + c] = y;
}

// ------------------------------------------------------------------
extern "C" void kernel_launch(void* const* d_in, const int* in_sizes, int n_in,
                              void* d_out, int out_size, void* d_ws, size_t ws_size,
                              hipStream_t stream)
{
    const float* x         = (const float*)d_in[0];
    const float* edge_attr = (const float*)d_in[1];
    const float* lin_w     = (const float*)d_in[2];
    const float* lin_b     = (const float*)d_in[3];
    const float* conv_W    = (const float*)d_in[4];
    const float* conv_asrc = (const float*)d_in[5];
    const float* conv_adst = (const float*)d_in[6];
    const float* fc_w1 = (const float*)d_in[7];
    const float* fc_b1 = (const float*)d_in[8];
    const float* bn_g1 = (const float*)d_in[9];
    const float* bn_b1 = (const float*)d_in[10];
    const float* fc_w2 = (const float*)d_in[11];
    const float* fc_b2 = (const float*)d_in[12];
    const float* bn_g2 = (const float*)d_in[13];
    const float* bn_b2 = (const float*)d_in[14];
    const float* fc_w3 = (const float*)d_in[15];
    const float* fc_b3 = (const float*)d_in[16];
    const float* bn_g3 = (const float*)d_in[17];
    const float* bn_b3 = (const float*)d_in[18];
    const int* edge_index = (const int*)d_in[19];
    const int* batch      = (const int*)d_in[20];
    const int* srcp = edge_index;
    const int* dstp = edge_index + N_EDGES;
    float* out = (float*)d_out;

    char* ws = (char*)d_ws;
    float* h_cur = (float*)ws;  ws += (size_t)N_NODES * 128 * 4;
    float* h_tmp = (float*)ws;  ws += (size_t)N_NODES * 128 * 4;
    __half* wx16 = (__half*)ws; ws += (size_t)N_NODES * 128 * 2;
    float* a_s   = (float*)ws;  ws += (size_t)N_NODES * 4 * 4;
    float* a_d   = (float*)ws;  ws += (size_t)N_NODES * 4 * 4;
    float* denom = (float*)ws;  ws += (size_t)N_NODES * 4 * 4;
    float* pooled= (float*)ws;  ws += (size_t)NGRAPH * 128 * 4;
    float* z1    = (float*)ws;  ws += (size_t)NGRAPH * 64 * 4;
    float* z2    = (float*)ws;  ws += (size_t)NGRAPH * 32 * 4;
    int* deg     = (int*)ws;    ws += (size_t)N_NODES * 4;
    int* offs    = (int*)ws;    ws += (size_t)(N_NODES + 4) * 4;
    int* cursor  = (int*)ws;    ws += (size_t)N_NODES * 4;
    int* csr     = (int*)ws;    ws += (size_t)N_EDGES * 4;
    int* srcs    = (int*)ws;    ws += (size_t)N_EDGES * 4;
    float4* walpha = (float4*)ws; ws += (size_t)N_EDGES * 16;
    int* cs      = (int*)ws;    ws += 64 * 4;
    int* cbase   = (int*)ws;    ws += 64 * 4;

    // --- CSR build ---
    k_zero_i<<<(N_NODES + 255) / 256, 256, 0, stream>>>(deg, N_NODES);
    k_deg<<<(N_EDGES + 255) / 256, 256, 0, stream>>>(dstp, deg);
    k_chunksum<<<NCHUNK, 256, 0, stream>>>(deg, cs);
    k_scanbase<<<1, 64, 0, stream>>>(cs, cbase, offs);
    k_scanlocal<<<NCHUNK, 1024, 0, stream>>>(deg, cbase, offs, cursor);
    k_fill<<<(N_EDGES + 255) / 256, 256, 0, stream>>>(dstp, cursor, csr);

    const int GGRID = (N_NODES + 63) / 64;

    // --- input linear (fp32 out) ---
    k_gemm<<<GGRID, 256, 0, stream>>>(x, lin_w, lin_b, h_cur, nullptr, N_NODES,
                                      nullptr, nullptr, nullptr, nullptr);

    // --- 3 residual scatter convs, 2 inner layers each ---
    for (int i = 0; i < 3; ++i) {
        const float* W0 = conv_W + (size_t)(i * 2 + 0) * 128 * 128;
        const float* W1 = conv_W + (size_t)(i * 2 + 1) * 128 * 128;
        const float* as0 = conv_asrc + (size_t)(i * 2 + 0) * 128;
        const float* as1 = conv_asrc + (size_t)(i * 2 + 1) * 128;
        const float* ad0 = conv_adst + (size_t)(i * 2 + 0) * 128;
        const float* ad1 = conv_adst + (size_t)(i * 2 + 1) * 128;

        k_gemm<<<GGRID, 256, 0, stream>>>(h_cur, W0, nullptr, nullptr, wx16,
                                          N_NODES, as0, ad0, a_s, a_d);
        k_alpha<<<N_NODES / 16, 256, 0, stream>>>(a_s, a_d, edge_attr, srcp,
                                                  csr, offs, srcs, walpha, denom);
        k_gather<<<N_NODES / 4, 256, 0, stream>>>(wx16, srcs, (const float*)walpha,
                                                  denom, offs, nullptr, h_tmp);

        k_gemm<<<GGRID, 256, 0, stream>>>(h_tmp, W1, nullptr, nullptr, wx16,
                                          N_NODES, as1, ad1, a_s, a_d);
        k_alpha<<<N_NODES / 16, 256, 0, stream>>>(a_s, a_d, edge_attr, srcp,
                                                  csr, offs, srcs, walpha, denom);
        k_gather<<<N_NODES / 4, 256, 0, stream>>>(wx16, srcs, (const float*)walpha,
                                                  denom, offs, h_cur, h_cur);
    }

    // --- pool + MLP head ---
    k_pool<<<NGRAPH, 128, 0, stream>>>(h_cur, batch, pooled);
    k_mlp<128, 64><<<64, 256, 0, stream>>>(pooled, fc_w1, fc_b1, bn_g1, bn_b1, z1, 1);
    k_mlp<64, 32><<<32, 256, 0, stream>>>(z1, fc_w2, fc_b2, bn_g2, bn_b2, z2, 1);
    k_mlp<32, 10><<<10, 256, 0, stream>>>(z2, fc_w3, fc_b3, bn_g3, bn_b3, out, 0);
}

// Round 3
// 682.979 us; speedup vs baseline: 2.1014x; 1.2654x over previous
//
#include <hip/hip_runtime.h>
#include <hip/hip_fp16.h>
#include <math.h>

#define N_NODES 50000
#define N_EDGES 640000
#define NGRAPH  256
#define SCHUNK  1024
#define NCHUNK  49   // ceil(50000/1024)

typedef _Float16 half8_t __attribute__((ext_vector_type(8)));
typedef float floatx4 __attribute__((ext_vector_type(4)));

// ------------------------------------------------------------------
// MFMA GEMM: C16[M,128] = half(A16[M,128] @ W[128,128] (+bias)).
// W (fp32, k-major) is transposed+converted to fp16 in LDS, XOR-swizzled.
// Block 256 = 4 waves; wave computes 16 rows x 128 cols via 8 N-tiles.
// Optional fused attention projections a_s/a_d (fp32).
// ------------------------------------------------------------------
__global__ __launch_bounds__(256) void k_gemm16(
    const __half* __restrict__ A, const float* __restrict__ W,
    const float* __restrict__ bias, __half* __restrict__ C16, int M,
    const float* __restrict__ asrc, const float* __restrict__ adst,
    float* __restrict__ a_s, float* __restrict__ a_d)
{
    __shared__ _Float16 Wt[128 * 128];   // 32 KB, W^T fp16
    int tid = threadIdx.x;

    // stage: element (k,n) -> Wt[n*128 + ((k>>3)^(n&15))*8 + (k&7)]
    #pragma unroll
    for (int i = 0; i < 32; ++i) {
        int idx = i * 256 + tid;     // 8192 k-pairs
        int kp = idx >> 7;           // 0..63
        int n = idx & 127;
        int k = kp * 2;
        float w0 = W[(size_t)k * 128 + n];
        float w1 = W[(size_t)(k + 1) * 128 + n];
        int slot = (k >> 3) ^ (n & 15);
        __half2 hv = __floats2half2_rn(w0, w1);
        *(__half2*)&Wt[n * 128 + slot * 8 + (k & 7)] = hv;
    }
    __syncthreads();

    int lane = tid & 63;
    int wv = tid >> 6;
    int r0 = blockIdx.x * 64 + wv * 16;
    int cl = lane & 15;
    int ks = lane >> 4;             // k-chunk group 0..3

    int arow = r0 + cl; if (arow >= M) arow = M - 1;
    const _Float16* Arow = (const _Float16*)A + (size_t)arow * 128 + ks * 8;
    half8_t afrag[4];
    #pragma unroll
    for (int kk = 0; kk < 4; ++kk)
        afrag[kk] = *(const half8_t*)(Arow + kk * 32);

    floatx4 acc[8];
    #pragma unroll
    for (int nt = 0; nt < 8; ++nt) acc[nt] = (floatx4){0.f, 0.f, 0.f, 0.f};

    #pragma unroll
    for (int kk = 0; kk < 4; ++kk) {
        #pragma unroll
        for (int nt = 0; nt < 8; ++nt) {
            int n = nt * 16 + cl;
            int slot = (kk * 4 + ks) ^ cl;
            half8_t bfrag = *(const half8_t*)&Wt[n * 128 + slot * 8];
            acc[nt] = __builtin_amdgcn_mfma_f32_16x16x32_f16(afrag[kk], bfrag, acc[nt], 0, 0, 0);
        }
    }

    int rg = lane >> 4;   // row group for C/D
    #pragma unroll
    for (int nt = 0; nt < 8; ++nt) {
        float bv = bias ? bias[nt * 16 + cl] : 0.f;
        #pragma unroll
        for (int j = 0; j < 4; ++j) {
            int row = r0 + rg * 4 + j;
            if (row < M)
                C16[(size_t)row * 128 + nt * 16 + cl] = __float2half(acc[nt][j] + bv);
        }
    }

    if (a_s) {
        float s[4][4], d[4][4];
        #pragma unroll
        for (int h = 0; h < 4; ++h)
            #pragma unroll
            for (int j = 0; j < 4; ++j) { s[h][j] = 0.f; d[h][j] = 0.f; }
        #pragma unroll
        for (int nt = 0; nt < 8; ++nt) {
            int h = nt >> 1;
            float as = asrc[h * 32 + (nt & 1) * 16 + cl];
            float ad = adst[h * 32 + (nt & 1) * 16 + cl];
            #pragma unroll
            for (int j = 0; j < 4; ++j) {
                s[h][j] += acc[nt][j] * as;
                d[h][j] += acc[nt][j] * ad;
            }
        }
        #pragma unroll
        for (int h = 0; h < 4; ++h)
            #pragma unroll
            for (int j = 0; j < 4; ++j)
                #pragma unroll
                for (int k = 1; k < 16; k <<= 1) {
                    s[h][j] += __shfl_xor(s[h][j], k);
                    d[h][j] += __shfl_xor(d[h][j], k);
                }
        if (cl == 0) {
            #pragma unroll
            for (int j = 0; j < 4; ++j) {
                int row = r0 + rg * 4 + j;
                if (row < M) {
                    #pragma unroll
                    for (int h = 0; h < 4; ++h) {
                        a_s[row * 4 + h] = s[h][j];
                        a_d[row * 4 + h] = d[h][j];
                    }
                }
            }
        }
    }
}

// ------------------------------------------------------------------
__global__ void k_cast16(const float* __restrict__ in, __half* __restrict__ out, int n4) {
    int i = blockIdx.x * blockDim.x + threadIdx.x;
    if (i < n4) {
        float4 v = ((const float4*)in)[i];
        __half2 a = __floats2half2_rn(v.x, v.y);
        __half2 b = __floats2half2_rn(v.z, v.w);
        ((__half2*)out)[i * 2] = a;
        ((__half2*)out)[i * 2 + 1] = b;
    }
}

__global__ void k_zero_i(int* p, int n) {
    int i = blockIdx.x * blockDim.x + threadIdx.x;
    if (i < n) p[i] = 0;
}

__global__ void k_zero_f(float* p, int n) {
    int i = blockIdx.x * blockDim.x + threadIdx.x;
    if (i < n) p[i] = 0.f;
}

// ------------------------------------------------------------------
// CSR build
// ------------------------------------------------------------------
__global__ void k_deg(const int* __restrict__ dst, int* deg) {
    int e = blockIdx.x * blockDim.x + threadIdx.x;
    if (e < N_EDGES) atomicAdd(&deg[dst[e]], 1);
}

__global__ __launch_bounds__(256) void k_chunksum(const int* __restrict__ deg, int* cs) {
    __shared__ int r[256];
    int b = blockIdx.x;
    int acc = 0;
    for (int i = threadIdx.x; i < SCHUNK; i += 256) {
        int idx = b * SCHUNK + i;
        if (idx < N_NODES) acc += deg[idx];
    }
    r[threadIdx.x] = acc; __syncthreads();
    for (int s = 128; s > 0; s >>= 1) {
        if (threadIdx.x < s) r[threadIdx.x] += r[threadIdx.x + s];
        __syncthreads();
    }
    if (threadIdx.x == 0) cs[b] = r[0];
}

__global__ void k_scanbase(const int* cs, int* base, int* offs) {
    if (threadIdx.x == 0) {
        int run = 0;
        for (int b = 0; b < NCHUNK; ++b) { base[b] = run; run += cs[b]; }
        offs[N_NODES] = run;
    }
}

__global__ __launch_bounds__(1024) void k_scanlocal(
    const int* __restrict__ deg, const int* __restrict__ base,
    int* offs, int* cursor)
{
    __shared__ int s[1024];
    int b = blockIdx.x, t = threadIdx.x;
    int idx = b * SCHUNK + t;
    int d = (idx < N_NODES) ? deg[idx] : 0;
    s[t] = d; __syncthreads();
    for (int off = 1; off < 1024; off <<= 1) {
        int v = (t >= off) ? s[t - off] : 0;
        __syncthreads();
        s[t] += v; __syncthreads();
    }
    if (idx < N_NODES) {
        int ex = s[t] - d + base[b];
        offs[idx] = ex; cursor[idx] = ex;
    }
}

__global__ void k_fill(const int* __restrict__ dst, int* cursor, int* csr) {
    int e = blockIdx.x * blockDim.x + threadIdx.x;
    if (e < N_EDGES) { int p = atomicAdd(&cursor[dst[e]], 1); csr[p] = e; }
}

// ------------------------------------------------------------------
// Alpha: per-node softmax over incident edges. 16 lanes per node.
// Writes CSR-ordered srcs[i], fp16 weights walpha[i][4], denom fp32.
// ------------------------------------------------------------------
__global__ __launch_bounds__(256) void k_alpha(
    const float* __restrict__ a_s, const float* __restrict__ a_d,
    const float* __restrict__ ea, const int* __restrict__ src,
    const int* __restrict__ csr, const int* __restrict__ offs,
    int* __restrict__ srcs, __half2* __restrict__ walpha,
    float* __restrict__ denom)
{
    int l = threadIdx.x & 15;
    int n = blockIdx.x * 16 + (threadIdx.x >> 4);
    int off0 = offs[n], off1 = offs[n + 1];
    float4 adn = *(const float4*)&a_d[n * 4];

    float m0 = -3e38f, m1 = -3e38f, m2 = -3e38f, m3 = -3e38f;
    for (int i = off0 + l; i < off1; i += 16) {
        int e = csr[i]; int s = src[e];
        float aev = ea[e];
        float4 as4 = *(const float4*)&a_s[s * 4];
        float v0 = as4.x + adn.x; v0 = (v0 > 0.f ? v0 : 0.2f * v0) * aev;
        float v1 = as4.y + adn.y; v1 = (v1 > 0.f ? v1 : 0.2f * v1) * aev;
        float v2 = as4.z + adn.z; v2 = (v2 > 0.f ? v2 : 0.2f * v2) * aev;
        float v3 = as4.w + adn.w; v3 = (v3 > 0.f ? v3 : 0.2f * v3) * aev;
        m0 = fmaxf(m0, v0); m1 = fmaxf(m1, v1);
        m2 = fmaxf(m2, v2); m3 = fmaxf(m3, v3);
    }
    #pragma unroll
    for (int k = 1; k < 16; k <<= 1) {
        m0 = fmaxf(m0, __shfl_xor(m0, k));
        m1 = fmaxf(m1, __shfl_xor(m1, k));
        m2 = fmaxf(m2, __shfl_xor(m2, k));
        m3 = fmaxf(m3, __shfl_xor(m3, k));
    }

    float s0 = 0.f, s1 = 0.f, s2 = 0.f, s3 = 0.f;
    for (int i = off0 + l; i < off1; i += 16) {
        int e = csr[i]; int s = src[e];
        float aev = ea[e];
        float4 as4 = *(const float4*)&a_s[s * 4];
        float v0 = as4.x + adn.x; v0 = (v0 > 0.f ? v0 : 0.2f * v0) * aev;
        float v1 = as4.y + adn.y; v1 = (v1 > 0.f ? v1 : 0.2f * v1) * aev;
        float v2 = as4.z + adn.z; v2 = (v2 > 0.f ? v2 : 0.2f * v2) * aev;
        float v3 = as4.w + adn.w; v3 = (v3 > 0.f ? v3 : 0.2f * v3) * aev;
        float w0 = __expf(v0 - m0), w1 = __expf(v1 - m1);
        float w2 = __expf(v2 - m2), w3 = __expf(v3 - m3);
        walpha[(size_t)i * 2]     = __floats2half2_rn(w0, w1);
        walpha[(size_t)i * 2 + 1] = __floats2half2_rn(w2, w3);
        srcs[i] = s;
        s0 += w0; s1 += w1; s2 += w2; s3 += w3;
    }
    #pragma unroll
    for (int k = 1; k < 16; k <<= 1) {
        s0 += __shfl_xor(s0, k); s1 += __shfl_xor(s1, k);
        s2 += __shfl_xor(s2, k); s3 += __shfl_xor(s3, k);
    }
    if (l == 0) *(float4*)&denom[n * 4] = make_float4(s0, s1, s2, s3);
}

// ------------------------------------------------------------------
// Gather: one wave per destination node, fp16 rows, unroll-4.
// ------------------------------------------------------------------
__global__ __launch_bounds__(256) void k_gather(
    const __half* __restrict__ wx16, const int* __restrict__ srcs,
    const __half* __restrict__ walpha, const float* __restrict__ denom,
    const int* __restrict__ offs, const __half* __restrict__ resid,
    __half* __restrict__ out)
{
    int lane = threadIdx.x & 63;
    int n = blockIdx.x * 4 + (threadIdx.x >> 6);
    int ht = lane >> 4;
    int col = lane * 2;
    int off0 = offs[n], off1 = offs[n + 1];

    float acc0 = 0.f, acc1 = 0.f;
    int i = off0;
    for (; i + 4 <= off1; i += 4) {
        int s0 = srcs[i], s1 = srcs[i + 1], s2 = srcs[i + 2], s3 = srcs[i + 3];
        float w0 = __half2float(walpha[(size_t)(i    ) * 4 + ht]);
        float w1 = __half2float(walpha[(size_t)(i + 1) * 4 + ht]);
        float w2 = __half2float(walpha[(size_t)(i + 2) * 4 + ht]);
        float w3 = __half2float(walpha[(size_t)(i + 3) * 4 + ht]);
        __half2 g0 = *(const __half2*)&wx16[(size_t)s0 * 128 + col];
        __half2 g1 = *(const __half2*)&wx16[(size_t)s1 * 128 + col];
        __half2 g2 = *(const __half2*)&wx16[(size_t)s2 * 128 + col];
        __half2 g3 = *(const __half2*)&wx16[(size_t)s3 * 128 + col];
        float2 f0 = __half22float2(g0), f1 = __half22float2(g1);
        float2 f2 = __half22float2(g2), f3 = __half22float2(g3);
        acc0 += w0 * f0.x + w1 * f1.x + w2 * f2.x + w3 * f3.x;
        acc1 += w0 * f0.y + w1 * f1.y + w2 * f2.y + w3 * f3.y;
    }
    for (; i < off1; ++i) {
        int s = srcs[i];
        float w = __half2float(walpha[(size_t)i * 4 + ht]);
        __half2 g = *(const __half2*)&wx16[(size_t)s * 128 + col];
        float2 f = __half22float2(g);
        acc0 += w * f.x; acc1 += w * f.y;
    }
    float inv = 1.f / (denom[n * 4 + ht] + 1e-16f);
    float r0 = acc0 * inv, r1 = acc1 * inv;
    r0 = r0 > 0.f ? r0 : expm1f(r0);
    r1 = r1 > 0.f ? r1 : expm1f(r1);
    if (resid) {
        float2 rv = __half22float2(*(const __half2*)&resid[(size_t)n * 128 + col]);
        r0 += rv.x; r1 += rv.y;
    }
    *(__half2*)&out[(size_t)n * 128 + col] = __floats2half2_rn(r0, r1);
}

// ------------------------------------------------------------------
// Pool: chunked partial sums + atomic flush at segment boundaries.
// Block covers 64 nodes; thread = (col, half), 32 nodes each.
// ------------------------------------------------------------------
__global__ __launch_bounds__(256) void k_pool2(
    const __half* __restrict__ h, const int* __restrict__ batch,
    float* __restrict__ pooled)
{
    int c = threadIdx.x & 127;
    int hf = threadIdx.x >> 7;
    int n0 = blockIdx.x * 64 + hf * 32;
    if (n0 >= N_NODES) return;
    int nend = n0 + 32; if (nend > N_NODES) nend = N_NODES;

    int g = batch[n0];
    float acc = 0.f;
    for (int n = n0; n < nend; ++n) {
        int bg = batch[n];
        if (bg != g) { atomicAdd(&pooled[g * 128 + c], acc); acc = 0.f; g = bg; }
        acc += __half2float(h[(size_t)n * 128 + c]);
    }
    atomicAdd(&pooled[g * 128 + c], acc);
}

// ------------------------------------------------------------------
// Linear + BatchNorm (+relu)
// ------------------------------------------------------------------
template <int K, int OC>
__global__ __launch_bounds__(256) void k_mlp(
    const float* __restrict__ in, const float* __restrict__ w,
    const float* __restrict__ b, const float* __restrict__ gam,
    const float* __restrict__ bet, float* __restrict__ out, int do_relu)
{
    __shared__ float2 red[256];
    int c = blockIdx.x, g = threadIdx.x;
    float val = b[c];
    #pragma unroll 8
    for (int k = 0; k < K; ++k) val += in[g * K + k] * w[k * OC + c];
    red[g] = make_float2(val, val * val);
    __syncthreads();
    for (int s = 128; s > 0; s >>= 1) {
        if (g < s) { red[g].x += red[g + s].x; red[g].y += red[g + s].y; }
        __syncthreads();
    }
    float mean = red[0].x * (1.f / 256.f);
    float var = red[0].y * (1.f / 256.f) - mean * mean;
    float y = (val - mean) * rsqrtf(var + 1e-5f) * gam[c] + bet[c];
    if (do_relu) y = fmaxf(y, 0.f);
    out[g * OC + c] = y;
}

// ------------------------------------------------------------------
extern "C" void kernel_launch(void* const* d_in, const int* in_sizes, int n_in,
                              void* d_out, int out_size, void* d_ws, size_t ws_size,
                              hipStream_t stream)
{
    const float* x         = (const float*)d_in[0];
    const float* edge_attr = (const float*)d_in[1];
    const float* lin_w     = (const float*)d_in[2];
    const float* lin_b     = (const float*)d_in[3];
    const float* conv_W    = (const float*)d_in[4];
    const float* conv_asrc = (const float*)d_in[5];
    const float* conv_adst = (const float*)d_in[6];
    const float* fc_w1 = (const float*)d_in[7];
    const float* fc_b1 = (const float*)d_in[8];
    const float* bn_g1 = (const float*)d_in[9];
    const float* bn_b1 = (const float*)d_in[10];
    const float* fc_w2 = (const float*)d_in[11];
    const float* fc_b2 = (const float*)d_in[12];
    const float* bn_g2 = (const float*)d_in[13];
    const float* bn_b2 = (const float*)d_in[14];
    const float* fc_w3 = (const float*)d_in[15];
    const float* fc_b3 = (const float*)d_in[16];
    const float* bn_g3 = (const float*)d_in[17];
    const float* bn_b3 = (const float*)d_in[18];
    const int* edge_index = (const int*)d_in[19];
    const int* batch      = (const int*)d_in[20];
    const int* srcp = edge_index;
    const int* dstp = edge_index + N_EDGES;
    float* out = (float*)d_out;

    char* ws = (char*)d_ws;
    __half* x16   = (__half*)ws; ws += (size_t)N_NODES * 128 * 2;
    __half* h_cur = (__half*)ws; ws += (size_t)N_NODES * 128 * 2;
    __half* h_tmp = (__half*)ws; ws += (size_t)N_NODES * 128 * 2;
    __half* wx16  = (__half*)ws; ws += (size_t)N_NODES * 128 * 2;
    float* a_s   = (float*)ws;  ws += (size_t)N_NODES * 4 * 4;
    float* a_d   = (float*)ws;  ws += (size_t)N_NODES * 4 * 4;
    float* denom = (float*)ws;  ws += (size_t)N_NODES * 4 * 4;
    float* pooled= (float*)ws;  ws += (size_t)NGRAPH * 128 * 4;
    float* z1    = (float*)ws;  ws += (size_t)NGRAPH * 64 * 4;
    float* z2    = (float*)ws;  ws += (size_t)NGRAPH * 32 * 4;
    int* deg     = (int*)ws;    ws += (size_t)N_NODES * 4;
    int* offs    = (int*)ws;    ws += (size_t)(N_NODES + 4) * 4;
    int* cursor  = (int*)ws;    ws += (size_t)N_NODES * 4;
    int* csr     = (int*)ws;    ws += (size_t)N_EDGES * 4;
    int* srcs    = (int*)ws;    ws += (size_t)N_EDGES * 4;
    __half2* walpha = (__half2*)ws; ws += (size_t)N_EDGES * 8;
    int* cs      = (int*)ws;    ws += 64 * 4;
    int* cbase   = (int*)ws;    ws += 64 * 4;

    // --- CSR build ---
    k_zero_i<<<(N_NODES + 255) / 256, 256, 0, stream>>>(deg, N_NODES);
    k_deg<<<(N_EDGES + 255) / 256, 256, 0, stream>>>(dstp, deg);
    k_chunksum<<<NCHUNK, 256, 0, stream>>>(deg, cs);
    k_scanbase<<<1, 64, 0, stream>>>(cs, cbase, offs);
    k_scanlocal<<<NCHUNK, 1024, 0, stream>>>(deg, cbase, offs, cursor);
    k_fill<<<(N_EDGES + 255) / 256, 256, 0, stream>>>(dstp, cursor, csr);

    // --- x -> fp16, zero pooled ---
    k_cast16<<<(N_NODES * 32 + 255) / 256, 256, 0, stream>>>(x, x16, N_NODES * 32);
    k_zero_f<<<(NGRAPH * 128 + 255) / 256, 256, 0, stream>>>(pooled, NGRAPH * 128);

    const int GGRID = (N_NODES + 63) / 64;

    // --- input linear ---
    k_gemm16<<<GGRID, 256, 0, stream>>>(x16, lin_w, lin_b, h_cur, N_NODES,
                                        nullptr, nullptr, nullptr, nullptr);

    // --- 3 residual scatter convs, 2 inner layers each ---
    for (int i = 0; i < 3; ++i) {
        const float* W0 = conv_W + (size_t)(i * 2 + 0) * 128 * 128;
        const float* W1 = conv_W + (size_t)(i * 2 + 1) * 128 * 128;
        const float* as0 = conv_asrc + (size_t)(i * 2 + 0) * 128;
        const float* as1 = conv_asrc + (size_t)(i * 2 + 1) * 128;
        const float* ad0 = conv_adst + (size_t)(i * 2 + 0) * 128;
        const float* ad1 = conv_adst + (size_t)(i * 2 + 1) * 128;

        k_gemm16<<<GGRID, 256, 0, stream>>>(h_cur, W0, nullptr, wx16, N_NODES,
                                            as0, ad0, a_s, a_d);
        k_alpha<<<N_NODES / 16, 256, 0, stream>>>(a_s, a_d, edge_attr, srcp,
                                                  csr, offs, srcs, walpha, denom);
        k_gather<<<N_NODES / 4, 256, 0, stream>>>(wx16, srcs, (const __half*)walpha,
                                                  denom, offs, nullptr, h_tmp);

        k_gemm16<<<GGRID, 256, 0, stream>>>(h_tmp, W1, nullptr, wx16, N_NODES,
                                            as1, ad1, a_s, a_d);
        k_alpha<<<N_NODES / 16, 256, 0, stream>>>(a_s, a_d, edge_attr, srcp,
                                                  csr, offs, srcs, walpha, denom);
        k_gather<<<N_NODES / 4, 256, 0, stream>>>(wx16, srcs, (const __half*)walpha,
                                                  denom, offs, h_cur, h_cur);
    }

    // --- pool + MLP head ---
    k_pool2<<<GGRID, 256, 0, stream>>>(h_cur, batch, pooled);
    k_mlp<128, 64><<<64, 256, 0, stream>>>(pooled, fc_w1, fc_b1, bn_g1, bn_b1, z1, 1);
    k_mlp<64, 32><<<32, 256, 0, stream>>>(z1, fc_w2, fc_b2, bn_g2, bn_b2, z2, 1);
    k_mlp<32, 10><<<10, 256, 0, stream>>>(z2, fc_w3, fc_b3, bn_g3, bn_b3, out, 0);
}

// Round 4
// 560.785 us; speedup vs baseline: 2.5593x; 1.2179x over previous
//
#include <hip/hip_runtime.h>
#include <hip/hip_fp16.h>
#include <math.h>

#define N_NODES 50000
#define N_EDGES 640000
#define NGRAPH  256
#define SCHUNK  1024
#define NCHUNK  49   // ceil(50000/1024)

typedef _Float16 half8_t __attribute__((ext_vector_type(8)));
typedef _Float16 half4_t __attribute__((ext_vector_type(4)));
typedef float floatx4 __attribute__((ext_vector_type(4)));

// ------------------------------------------------------------------
// Weight prep: convert all 7 [128,128] fp32 k-major weights into the
// fp16 transposed+swizzled layout the GEMM stages into LDS:
//   wt[m][n*128 + ((k>>3)^(n&15))*8 + (k&7)]
// ------------------------------------------------------------------
__global__ void k_wprep(const float* __restrict__ lin_w,
                        const float* __restrict__ conv_W,
                        _Float16* __restrict__ wt_g)
{
    int idx = blockIdx.x * 256 + threadIdx.x;
    if (idx >= 7 * 16384) return;
    int m = idx >> 14;
    int r = idx & 16383;
    int k = r >> 7;
    int n = r & 127;
    const float* W = (m == 0) ? lin_w : conv_W + (size_t)(m - 1) * 16384;
    float v = W[(size_t)k * 128 + n];
    int slot = (k >> 3) ^ (n & 15);
    wt_g[(size_t)m * 16384 + n * 128 + slot * 8 + (k & 7)] = (_Float16)v;
}

// ------------------------------------------------------------------
// MFMA GEMM: C16[M,128] = half(A16[M,128] @ W (+bias)).
// W comes pre-swizzled fp16 (wt); staging is a straight vector copy.
// Block 256 = 4 waves; wave computes 16 rows x 128 cols via 8 N-tiles.
// Optional fused attention projections a_s/a_d (fp32).
// ------------------------------------------------------------------
__global__ __launch_bounds__(256) void k_gemm16(
    const __half* __restrict__ A, const _Float16* __restrict__ wt,
    const float* __restrict__ bias, __half* __restrict__ C16, int M,
    const float* __restrict__ asrc, const float* __restrict__ adst,
    float* __restrict__ a_s, float* __restrict__ a_d)
{
    __shared__ _Float16 Wt[128 * 128];   // 32 KB
    int tid = threadIdx.x;
    {
        const float4* wsrc = (const float4*)wt;
        float4* wl = (float4*)Wt;
        #pragma unroll
        for (int r = 0; r < 8; ++r) wl[r * 256 + tid] = wsrc[r * 256 + tid];
    }
    __syncthreads();

    int lane = tid & 63;
    int wv = tid >> 6;
    int r0 = blockIdx.x * 64 + wv * 16;
    int cl = lane & 15;
    int ks = lane >> 4;             // k-chunk group 0..3

    int arow = r0 + cl; if (arow >= M) arow = M - 1;
    const _Float16* Arow = (const _Float16*)A + (size_t)arow * 128 + ks * 8;
    half8_t afrag[4];
    #pragma unroll
    for (int kk = 0; kk < 4; ++kk)
        afrag[kk] = *(const half8_t*)(Arow + kk * 32);

    floatx4 acc[8];
    #pragma unroll
    for (int nt = 0; nt < 8; ++nt) acc[nt] = (floatx4){0.f, 0.f, 0.f, 0.f};

    #pragma unroll
    for (int kk = 0; kk < 4; ++kk) {
        #pragma unroll
        for (int nt = 0; nt < 8; ++nt) {
            int n = nt * 16 + cl;
            int slot = (kk * 4 + ks) ^ cl;
            half8_t bfrag = *(const half8_t*)&Wt[n * 128 + slot * 8];
            acc[nt] = __builtin_amdgcn_mfma_f32_16x16x32_f16(afrag[kk], bfrag, acc[nt], 0, 0, 0);
        }
    }

    int rg = lane >> 4;   // row group for C/D
    #pragma unroll
    for (int nt = 0; nt < 8; ++nt) {
        float bv = bias ? bias[nt * 16 + cl] : 0.f;
        #pragma unroll
        for (int j = 0; j < 4; ++j) {
            int row = r0 + rg * 4 + j;
            if (row < M)
                C16[(size_t)row * 128 + nt * 16 + cl] = __float2half(acc[nt][j] + bv);
        }
    }

    if (a_s) {
        float s[4][4], d[4][4];
        #pragma unroll
        for (int h = 0; h < 4; ++h)
            #pragma unroll
            for (int j = 0; j < 4; ++j) { s[h][j] = 0.f; d[h][j] = 0.f; }
        #pragma unroll
        for (int nt = 0; nt < 8; ++nt) {
            int h = nt >> 1;
            float as = asrc[h * 32 + (nt & 1) * 16 + cl];
            float ad = adst[h * 32 + (nt & 1) * 16 + cl];
            #pragma unroll
            for (int j = 0; j < 4; ++j) {
                s[h][j] += acc[nt][j] * as;
                d[h][j] += acc[nt][j] * ad;
            }
        }
        #pragma unroll
        for (int h = 0; h < 4; ++h)
            #pragma unroll
            for (int j = 0; j < 4; ++j)
                #pragma unroll
                for (int k = 1; k < 16; k <<= 1) {
                    s[h][j] += __shfl_xor(s[h][j], k);
                    d[h][j] += __shfl_xor(d[h][j], k);
                }
        if (cl == 0) {
            #pragma unroll
            for (int j = 0; j < 4; ++j) {
                int row = r0 + rg * 4 + j;
                if (row < M) {
                    #pragma unroll
                    for (int h = 0; h < 4; ++h) {
                        a_s[row * 4 + h] = s[h][j];
                        a_d[row * 4 + h] = d[h][j];
                    }
                }
            }
        }
    }
}

// ------------------------------------------------------------------
__global__ void k_cast16(const float* __restrict__ in, __half* __restrict__ out, int n4) {
    int i = blockIdx.x * blockDim.x + threadIdx.x;
    if (i < n4) {
        float4 v = ((const float4*)in)[i];
        __half2 a = __floats2half2_rn(v.x, v.y);
        __half2 b = __floats2half2_rn(v.z, v.w);
        ((__half2*)out)[i * 2] = a;
        ((__half2*)out)[i * 2 + 1] = b;
    }
}

__global__ void k_zero_i(int* p, int n) {
    int i = blockIdx.x * blockDim.x + threadIdx.x;
    if (i < n) p[i] = 0;
}

__global__ void k_zero_f(float* p, int n) {
    int i = blockIdx.x * blockDim.x + threadIdx.x;
    if (i < n) p[i] = 0.f;
}

// ------------------------------------------------------------------
// CSR build (no csr[] array: k_fill writes srcs/eas directly)
// ------------------------------------------------------------------
__global__ void k_deg(const int* __restrict__ dst, int* deg) {
    int e = blockIdx.x * blockDim.x + threadIdx.x;
    if (e < N_EDGES) atomicAdd(&deg[dst[e]], 1);
}

__global__ __launch_bounds__(256) void k_chunksum(const int* __restrict__ deg, int* cs) {
    __shared__ int r[256];
    int b = blockIdx.x;
    int acc = 0;
    for (int i = threadIdx.x; i < SCHUNK; i += 256) {
        int idx = b * SCHUNK + i;
        if (idx < N_NODES) acc += deg[idx];
    }
    r[threadIdx.x] = acc; __syncthreads();
    for (int s = 128; s > 0; s >>= 1) {
        if (threadIdx.x < s) r[threadIdx.x] += r[threadIdx.x + s];
        __syncthreads();
    }
    if (threadIdx.x == 0) cs[b] = r[0];
}

__global__ void k_scanbase(const int* cs, int* base, int* offs) {
    if (threadIdx.x == 0) {
        int run = 0;
        for (int b = 0; b < NCHUNK; ++b) { base[b] = run; run += cs[b]; }
        offs[N_NODES] = run;
    }
}

__global__ __launch_bounds__(1024) void k_scanlocal(
    const int* __restrict__ deg, const int* __restrict__ base,
    int* offs, int* cursor)
{
    __shared__ int s[1024];
    int b = blockIdx.x, t = threadIdx.x;
    int idx = b * SCHUNK + t;
    int d = (idx < N_NODES) ? deg[idx] : 0;
    s[t] = d; __syncthreads();
    for (int off = 1; off < 1024; off <<= 1) {
        int v = (t >= off) ? s[t - off] : 0;
        __syncthreads();
        s[t] += v; __syncthreads();
    }
    if (idx < N_NODES) {
        int ex = s[t] - d + base[b];
        offs[idx] = ex; cursor[idx] = ex;
    }
}

__global__ void k_fill(const int* __restrict__ src, const int* __restrict__ dst,
                       const float* __restrict__ ea, int* cursor,
                       int* __restrict__ srcs, float* __restrict__ eas)
{
    int e = blockIdx.x * blockDim.x + threadIdx.x;
    if (e < N_EDGES) {
        int p = atomicAdd(&cursor[dst[e]], 1);
        srcs[p] = src[e];
        eas[p] = ea[e];
    }
}

// ------------------------------------------------------------------
// Alpha: per-node softmax over incident edges, 16 lanes per node.
// Pass 1: gather a_s once, compute logits v, cache as fp16 in walpha,
// track per-head max. Pass 2: re-read v SEQUENTIALLY (own writes),
// exp, rewrite walpha as unnormalized weights, reduce denom.
// ------------------------------------------------------------------
__global__ __launch_bounds__(256) void k_alpha(
    const float* __restrict__ a_s, const float* __restrict__ a_d,
    const int* __restrict__ srcs, const float* __restrict__ eas,
    const int* __restrict__ offs, __half2* __restrict__ walpha,
    float* __restrict__ denom)
{
    int l = threadIdx.x & 15;
    int n = blockIdx.x * 16 + (threadIdx.x >> 4);
    int off0 = offs[n], off1 = offs[n + 1];
    float4 adn = *(const float4*)&a_d[n * 4];

    float m0 = -3e38f, m1 = -3e38f, m2 = -3e38f, m3 = -3e38f;
    for (int i = off0 + l; i < off1; i += 16) {
        int s = srcs[i];
        float aev = eas[i];
        float4 as4 = *(const float4*)&a_s[s * 4];
        float v0 = as4.x + adn.x; v0 = (v0 > 0.f ? v0 : 0.2f * v0) * aev;
        float v1 = as4.y + adn.y; v1 = (v1 > 0.f ? v1 : 0.2f * v1) * aev;
        float v2 = as4.z + adn.z; v2 = (v2 > 0.f ? v2 : 0.2f * v2) * aev;
        float v3 = as4.w + adn.w; v3 = (v3 > 0.f ? v3 : 0.2f * v3) * aev;
        walpha[(size_t)i * 2]     = __floats2half2_rn(v0, v1);
        walpha[(size_t)i * 2 + 1] = __floats2half2_rn(v2, v3);
        m0 = fmaxf(m0, v0); m1 = fmaxf(m1, v1);
        m2 = fmaxf(m2, v2); m3 = fmaxf(m3, v3);
    }
    #pragma unroll
    for (int k = 1; k < 16; k <<= 1) {
        m0 = fmaxf(m0, __shfl_xor(m0, k));
        m1 = fmaxf(m1, __shfl_xor(m1, k));
        m2 = fmaxf(m2, __shfl_xor(m2, k));
        m3 = fmaxf(m3, __shfl_xor(m3, k));
    }

    float s0 = 0.f, s1 = 0.f, s2 = 0.f, s3 = 0.f;
    for (int i = off0 + l; i < off1; i += 16) {
        float2 va = __half22float2(walpha[(size_t)i * 2]);
        float2 vb = __half22float2(walpha[(size_t)i * 2 + 1]);
        float w0 = __expf(va.x - m0), w1 = __expf(va.y - m1);
        float w2 = __expf(vb.x - m2), w3 = __expf(vb.y - m3);
        walpha[(size_t)i * 2]     = __floats2half2_rn(w0, w1);
        walpha[(size_t)i * 2 + 1] = __floats2half2_rn(w2, w3);
        s0 += w0; s1 += w1; s2 += w2; s3 += w3;
    }
    #pragma unroll
    for (int k = 1; k < 16; k <<= 1) {
        s0 += __shfl_xor(s0, k); s1 += __shfl_xor(s1, k);
        s2 += __shfl_xor(s2, k); s3 += __shfl_xor(s3, k);
    }
    if (l == 0) *(float4*)&denom[n * 4] = make_float4(s0, s1, s2, s3);
}

// ------------------------------------------------------------------
// Gather: one wave per destination node. Lanes 0-31 = even edge,
// 32-63 = odd edge; each lane covers 4 cols (8B half4 gather).
// Cross-half merge via shfl_xor(32). Unroll-4 = 8 edges in flight.
// ------------------------------------------------------------------
__global__ __launch_bounds__(256) void k_gather(
    const __half* __restrict__ wx16, const int* __restrict__ srcs,
    const __half* __restrict__ walpha, const float* __restrict__ denom,
    const int* __restrict__ offs, const __half* __restrict__ resid,
    __half* __restrict__ out)
{
    int lane = threadIdx.x & 63;
    int n = blockIdx.x * 4 + (threadIdx.x >> 6);
    int half_ = lane >> 5;
    int cg = lane & 31;
    int c0 = cg * 4;
    int ht = cg >> 3;
    int off0 = offs[n], off1 = offs[n + 1];
    const _Float16* wx = (const _Float16*)wx16;

    float a0 = 0.f, a1 = 0.f, a2 = 0.f, a3 = 0.f;
    int i = off0;
    for (; i + 8 <= off1; i += 8) {
        #pragma unroll
        for (int u = 0; u < 4; ++u) {
            int e = i + u * 2 + half_;
            int s = srcs[e];
            float w = __half2float(((const __half*)walpha)[(size_t)e * 4 + ht]);
            half4_t g = *(const half4_t*)&wx[(size_t)s * 128 + c0];
            a0 += w * (float)g[0]; a1 += w * (float)g[1];
            a2 += w * (float)g[2]; a3 += w * (float)g[3];
        }
    }
    for (; i < off1; i += 2) {
        int e = i + half_;
        if (e < off1) {
            int s = srcs[e];
            float w = __half2float(((const __half*)walpha)[(size_t)e * 4 + ht]);
            half4_t g = *(const half4_t*)&wx[(size_t)s * 128 + c0];
            a0 += w * (float)g[0]; a1 += w * (float)g[1];
            a2 += w * (float)g[2]; a3 += w * (float)g[3];
        }
    }
    a0 += __shfl_xor(a0, 32); a1 += __shfl_xor(a1, 32);
    a2 += __shfl_xor(a2, 32); a3 += __shfl_xor(a3, 32);

    if (half_ == 0) {
        float inv = 1.f / (denom[n * 4 + ht] + 1e-16f);
        float r0 = a0 * inv, r1 = a1 * inv, r2 = a2 * inv, r3 = a3 * inv;
        r0 = r0 > 0.f ? r0 : expm1f(r0);
        r1 = r1 > 0.f ? r1 : expm1f(r1);
        r2 = r2 > 0.f ? r2 : expm1f(r2);
        r3 = r3 > 0.f ? r3 : expm1f(r3);
        if (resid) {
            half4_t rv = *(const half4_t*)((const _Float16*)resid + (size_t)n * 128 + c0);
            r0 += (float)rv[0]; r1 += (float)rv[1];
            r2 += (float)rv[2]; r3 += (float)rv[3];
        }
        half4_t o;
        o[0] = (_Float16)r0; o[1] = (_Float16)r1;
        o[2] = (_Float16)r2; o[3] = (_Float16)r3;
        *(half4_t*)((_Float16*)out + (size_t)n * 128 + c0) = o;
    }
}

// ------------------------------------------------------------------
// Pool: chunked partial sums + atomic flush at segment boundaries.
// ------------------------------------------------------------------
__global__ __launch_bounds__(256) void k_pool2(
    const __half* __restrict__ h, const int* __restrict__ batch,
    float* __restrict__ pooled)
{
    int c = threadIdx.x & 127;
    int hf = threadIdx.x >> 7;
    int n0 = blockIdx.x * 64 + hf * 32;
    if (n0 >= N_NODES) return;
    int nend = n0 + 32; if (nend > N_NODES) nend = N_NODES;

    int g = batch[n0];
    float acc = 0.f;
    for (int n = n0; n < nend; ++n) {
        int bg = batch[n];
        if (bg != g) { atomicAdd(&pooled[g * 128 + c], acc); acc = 0.f; g = bg; }
        acc += __half2float(h[(size_t)n * 128 + c]);
    }
    atomicAdd(&pooled[g * 128 + c], acc);
}

// ------------------------------------------------------------------
// Linear + BatchNorm (+relu)
// ------------------------------------------------------------------
template <int K, int OC>
__global__ __launch_bounds__(256) void k_mlp(
    const float* __restrict__ in, const float* __restrict__ w,
    const float* __restrict__ b, const float* __restrict__ gam,
    const float* __restrict__ bet, float* __restrict__ out, int do_relu)
{
    __shared__ float2 red[256];
    int c = blockIdx.x, g = threadIdx.x;
    float val = b[c];
    #pragma unroll 8
    for (int k = 0; k < K; ++k) val += in[g * K + k] * w[k * OC + c];
    red[g] = make_float2(val, val * val);
    __syncthreads();
    for (int s = 128; s > 0; s >>= 1) {
        if (g < s) { red[g].x += red[g + s].x; red[g].y += red[g + s].y; }
        __syncthreads();
    }
    float mean = red[0].x * (1.f / 256.f);
    float var = red[0].y * (1.f / 256.f) - mean * mean;
    float y = (val - mean) * rsqrtf(var + 1e-5f) * gam[c] + bet[c];
    if (do_relu) y = fmaxf(y, 0.f);
    out[g * OC + c] = y;
}

// ------------------------------------------------------------------
extern "C" void kernel_launch(void* const* d_in, const int* in_sizes, int n_in,
                              void* d_out, int out_size, void* d_ws, size_t ws_size,
                              hipStream_t stream)
{
    const float* x         = (const float*)d_in[0];
    const float* edge_attr = (const float*)d_in[1];
    const float* lin_w     = (const float*)d_in[2];
    const float* lin_b     = (const float*)d_in[3];
    const float* conv_W    = (const float*)d_in[4];
    const float* conv_asrc = (const float*)d_in[5];
    const float* conv_adst = (const float*)d_in[6];
    const float* fc_w1 = (const float*)d_in[7];
    const float* fc_b1 = (const float*)d_in[8];
    const float* bn_g1 = (const float*)d_in[9];
    const float* bn_b1 = (const float*)d_in[10];
    const float* fc_w2 = (const float*)d_in[11];
    const float* fc_b2 = (const float*)d_in[12];
    const float* bn_g2 = (const float*)d_in[13];
    const float* bn_b2 = (const float*)d_in[14];
    const float* fc_w3 = (const float*)d_in[15];
    const float* fc_b3 = (const float*)d_in[16];
    const float* bn_g3 = (const float*)d_in[17];
    const float* bn_b3 = (const float*)d_in[18];
    const int* edge_index = (const int*)d_in[19];
    const int* batch      = (const int*)d_in[20];
    const int* srcp = edge_index;
    const int* dstp = edge_index + N_EDGES;
    float* out = (float*)d_out;

    char* ws = (char*)d_ws;
    __half* x16   = (__half*)ws; ws += (size_t)N_NODES * 128 * 2;
    __half* h_cur = (__half*)ws; ws += (size_t)N_NODES * 128 * 2;
    __half* h_tmp = (__half*)ws; ws += (size_t)N_NODES * 128 * 2;
    __half* wx16  = (__half*)ws; ws += (size_t)N_NODES * 128 * 2;
    float* a_s   = (float*)ws;  ws += (size_t)N_NODES * 4 * 4;
    float* a_d   = (float*)ws;  ws += (size_t)N_NODES * 4 * 4;
    float* denom = (float*)ws;  ws += (size_t)N_NODES * 4 * 4;
    float* pooled= (float*)ws;  ws += (size_t)NGRAPH * 128 * 4;
    float* z1    = (float*)ws;  ws += (size_t)NGRAPH * 64 * 4;
    float* z2    = (float*)ws;  ws += (size_t)NGRAPH * 32 * 4;
    int* deg     = (int*)ws;    ws += (size_t)N_NODES * 4;
    int* offs    = (int*)ws;    ws += (size_t)(N_NODES + 4) * 4;
    int* cursor  = (int*)ws;    ws += (size_t)N_NODES * 4;
    int* srcs    = (int*)ws;    ws += (size_t)N_EDGES * 4;
    float* eas   = (float*)ws;  ws += (size_t)N_EDGES * 4;
    __half2* walpha = (__half2*)ws; ws += (size_t)N_EDGES * 8;
    _Float16* wt_g = (_Float16*)ws; ws += (size_t)7 * 16384 * 2;
    int* cs      = (int*)ws;    ws += 64 * 4;
    int* cbase   = (int*)ws;    ws += 64 * 4;

    // --- CSR build + weight prep + casts ---
    k_zero_i<<<(N_NODES + 255) / 256, 256, 0, stream>>>(deg, N_NODES);
    k_deg<<<(N_EDGES + 255) / 256, 256, 0, stream>>>(dstp, deg);
    k_chunksum<<<NCHUNK, 256, 0, stream>>>(deg, cs);
    k_scanbase<<<1, 64, 0, stream>>>(cs, cbase, offs);
    k_scanlocal<<<NCHUNK, 1024, 0, stream>>>(deg, cbase, offs, cursor);
    k_fill<<<(N_EDGES + 255) / 256, 256, 0, stream>>>(srcp, dstp, edge_attr,
                                                      cursor, srcs, eas);
    k_wprep<<<(7 * 16384 + 255) / 256, 256, 0, stream>>>(lin_w, conv_W, wt_g);
    k_cast16<<<(N_NODES * 32 + 255) / 256, 256, 0, stream>>>(x, x16, N_NODES * 32);
    k_zero_f<<<(NGRAPH * 128 + 255) / 256, 256, 0, stream>>>(pooled, NGRAPH * 128);

    const int GGRID = (N_NODES + 63) / 64;

    // --- input linear ---
    k_gemm16<<<GGRID, 256, 0, stream>>>(x16, wt_g, lin_b, h_cur, N_NODES,
                                        nullptr, nullptr, nullptr, nullptr);

    // --- 3 residual scatter convs, 2 inner layers each ---
    for (int i = 0; i < 3; ++i) {
        const _Float16* W0 = wt_g + (size_t)(1 + i * 2 + 0) * 16384;
        const _Float16* W1 = wt_g + (size_t)(1 + i * 2 + 1) * 16384;
        const float* as0 = conv_asrc + (size_t)(i * 2 + 0) * 128;
        const float* as1 = conv_asrc + (size_t)(i * 2 + 1) * 128;
        const float* ad0 = conv_adst + (size_t)(i * 2 + 0) * 128;
        const float* ad1 = conv_adst + (size_t)(i * 2 + 1) * 128;

        k_gemm16<<<GGRID, 256, 0, stream>>>(h_cur, W0, nullptr, wx16, N_NODES,
                                            as0, ad0, a_s, a_d);
        k_alpha<<<N_NODES / 16, 256, 0, stream>>>(a_s, a_d, srcs, eas,
                                                  offs, walpha, denom);
        k_gather<<<N_NODES / 4, 256, 0, stream>>>(wx16, srcs, (const __half*)walpha,
                                                  denom, offs, nullptr, h_tmp);

        k_gemm16<<<GGRID, 256, 0, stream>>>(h_tmp, W1, nullptr, wx16, N_NODES,
                                            as1, ad1, a_s, a_d);
        k_alpha<<<N_NODES / 16, 256, 0, stream>>>(a_s, a_d, srcs, eas,
                                                  offs, walpha, denom);
        k_gather<<<N_NODES / 4, 256, 0, stream>>>(wx16, srcs, (const __half*)walpha,
                                                  denom, offs, h_cur, h_cur);
    }

    // --- pool + MLP head ---
    k_pool2<<<GGRID, 256, 0, stream>>>(h_cur, batch, pooled);
    k_mlp<128, 64><<<64, 256, 0, stream>>>(pooled, fc_w1, fc_b1, bn_g1, bn_b1, z1, 1);
    k_mlp<64, 32><<<32, 256, 0, stream>>>(z1, fc_w2, fc_b2, bn_g2, bn_b2, z2, 1);
    k_mlp<32, 10><<<10, 256, 0, stream>>>(z2, fc_w3, fc_b3, bn_g3, bn_b3, out, 0);
}